// Round 1
// baseline (1061.980 us; speedup 1.0000x reference)
//
#include <hip/hip_runtime.h>
#include <hip/hip_bf16.h>

// ---------------------------------------------------------------------------
// GraphSAGE 3-layer forward, fp32 (correctness-first round).
// Per layer: msg = segment_sum(h[src], dst); deg = segment_sum(1, dst);
//            out = act(h[:n_dst] @ Ws + (msg/max(deg,1)) @ Wn + b)
// Strategy: aggregate in input-feature dim (atomics), then fused dual-GEMM
// treating K = 2*K1 with the first half reading h_dst and second half msg*invdeg.
// ---------------------------------------------------------------------------

// One thread per (edge, feature). feat is a power of two (128 or 256).
__global__ void scatter_add_kernel(const float* __restrict__ h,
                                   const int* __restrict__ src,
                                   const int* __restrict__ dst,
                                   float* __restrict__ msg,
                                   float* __restrict__ deg,
                                   int n_edge, int feat_log2) {
    int gid = blockIdx.x * blockDim.x + threadIdx.x;
    int e = gid >> feat_log2;
    if (e >= n_edge) return;
    int feat = 1 << feat_log2;
    int f = gid & (feat - 1);
    int s = src[e];
    int d = dst[e];
    float v = h[(size_t)s * feat + f];
    atomicAdd(&msg[(size_t)d * feat + f], v);
    if (f == 0) atomicAdd(&deg[d], 1.0f);
}

__global__ void invdeg_kernel(float* __restrict__ deg, int n) {
    int i = blockIdx.x * blockDim.x + threadIdx.x;
    if (i < n) deg[i] = 1.0f / fmaxf(deg[i], 1.0f);
}

// Fused SAGE GEMM: Out[M x N] = act( Hdst @ Ws + (Msg * invdeg_row) @ Wn + b )
// K total = 2*K1; k-tiles [0, K1) read Hdst/Ws, [K1, 2K1) read Msg/Wn.
// BM=BN=64, BK=16, 256 threads, 4x4 micro-tile per thread.
// M must be a multiple of 64 (holds: 51200, 5120, 1024). N bounds-checked.
template <int RELU>
__launch_bounds__(256)
__global__ void sage_gemm_kernel(const float* __restrict__ Hdst,
                                 const float* __restrict__ Msg,
                                 const float* __restrict__ invdeg,
                                 const float* __restrict__ Ws,
                                 const float* __restrict__ Wn,
                                 const float* __restrict__ bias,
                                 float* __restrict__ Out,
                                 int N, int K1) {
    __shared__ float As[16][68];  // [k][m], padded: stride 68 keeps 16B align + no conflicts
    __shared__ float Bs[16][68];  // [k][n]

    const int t  = threadIdx.x;
    const int tx = t & 15;        // 0..15 -> n micro-tile
    const int ty = t >> 4;        // 0..15 -> m micro-tile

    // A-tile load mapping: 64 rows x 16 k, float4 along k
    const int a_m = t >> 2;          // 0..63
    const int a_k = (t & 3) << 2;    // 0,4,8,12
    // B-tile load mapping: 16 k-rows x 64 n, float4 along n
    const int b_k = t >> 4;          // 0..15
    const int b_n = (t & 15) << 2;   // 0..60

    const long gm  = (long)blockIdx.y * 64 + a_m;
    const int  gn0 = blockIdx.x * 64 + b_n;
    const bool n_vec4 = ((N & 3) == 0);

    float acc[4][4];
#pragma unroll
    for (int i = 0; i < 4; ++i)
#pragma unroll
        for (int j = 0; j < 4; ++j) acc[i][j] = 0.0f;

    const int tilesPerHalf = K1 >> 4;
    const int Ktiles = tilesPerHalf * 2;

    for (int kt = 0; kt < Ktiles; ++kt) {
        const bool neigh = (kt >= tilesPerHalf);
        const int k0 = (neigh ? (kt - tilesPerHalf) : kt) << 4;

        // --- stage A ---
        {
            const float* Abase = neigh ? Msg : Hdst;
            const float4 v = *(const float4*)(Abase + gm * K1 + k0 + a_k);
            const float scale = neigh ? invdeg[gm] : 1.0f;
            As[a_k + 0][a_m] = v.x * scale;
            As[a_k + 1][a_m] = v.y * scale;
            As[a_k + 2][a_m] = v.z * scale;
            As[a_k + 3][a_m] = v.w * scale;
        }
        // --- stage B ---
        {
            const float* Wbase = neigh ? Wn : Ws;
            const float* rowp = Wbase + (size_t)(k0 + b_k) * N;
            if (n_vec4 && gn0 + 3 < N) {
                const float4 w = *(const float4*)(rowp + gn0);
                Bs[b_k][b_n + 0] = w.x;
                Bs[b_k][b_n + 1] = w.y;
                Bs[b_k][b_n + 2] = w.z;
                Bs[b_k][b_n + 3] = w.w;
            } else {
#pragma unroll
                for (int u = 0; u < 4; ++u)
                    Bs[b_k][b_n + u] = (gn0 + u < N) ? rowp[gn0 + u] : 0.0f;
            }
        }
        __syncthreads();

#pragma unroll
        for (int kk = 0; kk < 16; ++kk) {
            const float4 av = *(const float4*)&As[kk][ty << 2];
            const float4 bv = *(const float4*)&Bs[kk][tx << 2];
            const float a[4] = {av.x, av.y, av.z, av.w};
            const float b[4] = {bv.x, bv.y, bv.z, bv.w};
#pragma unroll
            for (int i = 0; i < 4; ++i)
#pragma unroll
                for (int j = 0; j < 4; ++j) acc[i][j] += a[i] * b[j];
        }
        __syncthreads();
    }

    // --- epilogue ---
    const int om = blockIdx.y * 64 + (ty << 2);
    const int on = blockIdx.x * 64 + (tx << 2);
#pragma unroll
    for (int i = 0; i < 4; ++i) {
#pragma unroll
        for (int j = 0; j < 4; ++j) {
            const int n = on + j;
            if (n < N) {
                float v = acc[i][j] + bias[n];
                if (RELU) v = fmaxf(v, 0.0f);
                Out[(size_t)(om + i) * N + n] = v;
            }
        }
    }
}

extern "C" void kernel_launch(void* const* d_in, const int* in_sizes, int n_in,
                              void* d_out, int out_size, void* d_ws, size_t ws_size,
                              hipStream_t stream) {
    const float* x    = (const float*)d_in[0];
    const int*   src0 = (const int*)d_in[1];
    const int*   dst0 = (const int*)d_in[2];
    const int*   src1 = (const int*)d_in[3];
    const int*   dst1 = (const int*)d_in[4];
    const int*   src2 = (const int*)d_in[5];
    const int*   dst2 = (const int*)d_in[6];
    const float* Ws0  = (const float*)d_in[7];
    const float* Wn0  = (const float*)d_in[8];
    const float* b0   = (const float*)d_in[9];
    const float* Ws1  = (const float*)d_in[10];
    const float* Wn1  = (const float*)d_in[11];
    const float* b1   = (const float*)d_in[12];
    const float* Ws2  = (const float*)d_in[13];
    const float* Wn2  = (const float*)d_in[14];
    const float* b2   = (const float*)d_in[15];
    float* out = (float*)d_out;

    char* ws = (char*)d_ws;
    // Layer-0 buffers
    float* msg0 = (float*)(ws + 0);          // 51200*128*4 = 26,214,400
    float* deg0 = (float*)(ws + 26214400);   // 51200*4     =    204,800
    float* h1   = (float*)(ws + 26419200);   // 51200*256*4 = 52,428,800 (end 78,848,000)
    // Layer-1/2 buffers reuse msg0's region (free after gemm0)
    float* msg1 = (float*)(ws + 0);          // 5120*256*4 = 5,242,880
    float* deg1 = (float*)(ws + 5242880);    // 5120*4
    float* h2   = (float*)(ws + 5263360);    // 5120*256*4
    float* msg2 = (float*)(ws + 10506240);   // 1024*256*4 = 1,048,576
    float* deg2 = (float*)(ws + 11554816);   // 1024*4

    // ---- Layer 0: feat=128, edges=768000, n_dst=51200 ----
    hipMemsetAsync(msg0, 0, 26419200, stream);  // msg0 + deg0 (contiguous)
    {
        long total = (long)768000 << 7;
        scatter_add_kernel<<<(unsigned)((total + 255) / 256), 256, 0, stream>>>(
            x, src0, dst0, msg0, deg0, 768000, 7);
        invdeg_kernel<<<(51200 + 255) / 256, 256, 0, stream>>>(deg0, 51200);
        dim3 grid(256 / 64, 51200 / 64);
        sage_gemm_kernel<1><<<grid, 256, 0, stream>>>(x, msg0, deg0, Ws0, Wn0, b0, h1, 256, 128);
    }

    // ---- Layer 1: feat=256, edges=51200, n_dst=5120 ----
    hipMemsetAsync(msg1, 0, 5263360, stream);   // msg1 + deg1
    {
        long total = (long)51200 << 8;
        scatter_add_kernel<<<(unsigned)((total + 255) / 256), 256, 0, stream>>>(
            h1, src1, dst1, msg1, deg1, 51200, 8);
        invdeg_kernel<<<(5120 + 255) / 256, 256, 0, stream>>>(deg1, 5120);
        dim3 grid(256 / 64, 5120 / 64);
        sage_gemm_kernel<1><<<grid, 256, 0, stream>>>(h1, msg1, deg1, Ws1, Wn1, b1, h2, 256, 256);
    }

    // ---- Layer 2: feat=256, edges=5120, n_dst=1024, N=47, no relu ----
    hipMemsetAsync(msg2, 0, 11558912 - 10506240, stream);  // msg2 + deg2
    {
        long total = (long)5120 << 8;
        scatter_add_kernel<<<(unsigned)((total + 255) / 256), 256, 0, stream>>>(
            h2, src2, dst2, msg2, deg2, 5120, 8);
        invdeg_kernel<<<(1024 + 255) / 256, 256, 0, stream>>>(deg2, 1024);
        dim3 grid(1, 1024 / 64);
        sage_gemm_kernel<0><<<grid, 256, 0, stream>>>(h2, msg2, deg2, Ws2, Wn2, b2, out, 47, 256);
    }
}

// Round 2
// 775.028 us; speedup vs baseline: 1.3702x; 1.3702x over previous
//
#include <hip/hip_runtime.h>

// ---------------------------------------------------------------------------
// GraphSAGE 3-layer forward. Round 2:
//  - CSR build (hist -> scan -> fill) + gather-based mean aggregation
//    (kills the 408 MB/layer atomic write-through seen in round 1)
//  - bf16 MFMA GEMM (16x16x32), fp32 accumulate, bf16 intermediate h
// ---------------------------------------------------------------------------

typedef __bf16 bf16x8 __attribute__((ext_vector_type(8)));
typedef float f32x4 __attribute__((ext_vector_type(4)));

static __device__ __forceinline__ unsigned short f32_to_bf16(float f) {
    unsigned u = __float_as_uint(f);
    u += 0x7fffu + ((u >> 16) & 1u);   // round-nearest-even
    return (unsigned short)(u >> 16);
}

// ---------------- CSR build ----------------

__global__ void hist_kernel(const int* __restrict__ dst, int* __restrict__ counts, int n_edge) {
    int i = blockIdx.x * 256 + threadIdx.x;
    if (i < n_edge) atomicAdd(&counts[dst[i]], 1);
}

// Single-block exclusive scan: counts[0..n) -> offsets[0..n], cursor copy.
__global__ void scan_kernel(const int* __restrict__ counts, int* __restrict__ offsets,
                            int* __restrict__ cursor, int n) {
    __shared__ int wsum[4];
    __shared__ int s_carry;
    if (threadIdx.x == 0) s_carry = 0;
    __syncthreads();
    const int lane = threadIdx.x & 63;
    const int wid = threadIdx.x >> 6;
    for (int base = 0; base < n; base += 2048) {
        int idx = base + threadIdx.x * 8;
        int v[8];
#pragma unroll
        for (int u = 0; u < 8; ++u) v[u] = (idx + u < n) ? counts[idx + u] : 0;
        int tsum = 0;
#pragma unroll
        for (int u = 0; u < 8; ++u) { int t = v[u]; v[u] = tsum; tsum += t; }
        int incl = tsum;
#pragma unroll
        for (int d = 1; d < 64; d <<= 1) {
            int t = __shfl_up(incl, d, 64);
            if (lane >= d) incl += t;
        }
        int wexcl = incl - tsum;
        if (lane == 63) wsum[wid] = incl;
        __syncthreads();
        int wbase = 0;
        for (int w = 0; w < wid; ++w) wbase += wsum[w];
        int carry = s_carry;
        int pre = carry + wbase + wexcl;
#pragma unroll
        for (int u = 0; u < 8; ++u)
            if (idx + u < n) { int o = pre + v[u]; offsets[idx + u] = o; cursor[idx + u] = o; }
        __syncthreads();
        if (threadIdx.x == 0) s_carry = carry + wsum[0] + wsum[1] + wsum[2] + wsum[3];
        __syncthreads();
    }
    if (threadIdx.x == 0) offsets[n] = s_carry;
}

__global__ void fill_kernel(const int* __restrict__ src, const int* __restrict__ dst,
                            int* __restrict__ cursor, int* __restrict__ csr_src, int n_edge) {
    int i = blockIdx.x * 256 + threadIdx.x;
    if (i < n_edge) {
        int pos = atomicAdd(&cursor[dst[i]], 1);
        csr_src[pos] = src[i];
    }
}

// ---------------- gather (mean aggregate) ----------------

// feat=128, fp32 input rows, bf16 output. One wave per dst row; lane holds float2.
__global__ void gather_f32_128(const float* __restrict__ h, const int* __restrict__ csr_src,
                               const int* __restrict__ offsets, unsigned short* __restrict__ out,
                               int n_dst) {
    int row = (blockIdx.x * blockDim.x + threadIdx.x) >> 6;
    if (row >= n_dst) return;
    int lane = threadIdx.x & 63;
    int beg = offsets[row], end = offsets[row + 1];
    const float2* hp = (const float2*)h;  // 64 float2 per row
    float ax = 0.f, ay = 0.f;
    int i = beg;
    for (; i + 1 < end; i += 2) {
        int s0 = csr_src[i], s1 = csr_src[i + 1];
        float2 v0 = hp[(size_t)s0 * 64 + lane];
        float2 v1 = hp[(size_t)s1 * 64 + lane];
        ax += v0.x + v1.x; ay += v0.y + v1.y;
    }
    if (i < end) {
        int s = csr_src[i];
        float2 v = hp[(size_t)s * 64 + lane];
        ax += v.x; ay += v.y;
    }
    float inv = 1.0f / fmaxf((float)(end - beg), 1.0f);
    unsigned pack = (unsigned)f32_to_bf16(ax * inv) | ((unsigned)f32_to_bf16(ay * inv) << 16);
    ((unsigned*)out)[(size_t)row * 64 + lane] = pack;
}

// feat=256, bf16 input rows, bf16 output. One wave per dst row; lane holds 4 bf16.
__global__ void gather_bf16_256(const unsigned short* __restrict__ h, const int* __restrict__ csr_src,
                                const int* __restrict__ offsets, unsigned short* __restrict__ out,
                                int n_dst) {
    int row = (blockIdx.x * blockDim.x + threadIdx.x) >> 6;
    if (row >= n_dst) return;
    int lane = threadIdx.x & 63;
    int beg = offsets[row], end = offsets[row + 1];
    const uint2* hp = (const uint2*)h;  // 64 x (4 bf16) per row
    float a0 = 0.f, a1 = 0.f, a2 = 0.f, a3 = 0.f;
    int i = beg;
    for (; i + 1 < end; i += 2) {
        int s0 = csr_src[i], s1 = csr_src[i + 1];
        uint2 u0 = hp[(size_t)s0 * 64 + lane];
        uint2 u1 = hp[(size_t)s1 * 64 + lane];
        a0 += __uint_as_float(u0.x << 16) + __uint_as_float(u1.x << 16);
        a1 += __uint_as_float(u0.x & 0xffff0000u) + __uint_as_float(u1.x & 0xffff0000u);
        a2 += __uint_as_float(u0.y << 16) + __uint_as_float(u1.y << 16);
        a3 += __uint_as_float(u0.y & 0xffff0000u) + __uint_as_float(u1.y & 0xffff0000u);
    }
    if (i < end) {
        int s = csr_src[i];
        uint2 u = hp[(size_t)s * 64 + lane];
        a0 += __uint_as_float(u.x << 16);
        a1 += __uint_as_float(u.x & 0xffff0000u);
        a2 += __uint_as_float(u.y << 16);
        a3 += __uint_as_float(u.y & 0xffff0000u);
    }
    float inv = 1.0f / fmaxf((float)(end - beg), 1.0f);
    uint2 o;
    o.x = (unsigned)f32_to_bf16(a0 * inv) | ((unsigned)f32_to_bf16(a1 * inv) << 16);
    o.y = (unsigned)f32_to_bf16(a2 * inv) | ((unsigned)f32_to_bf16(a3 * inv) << 16);
    ((uint2*)out)[(size_t)row * 64 + lane] = o;
}

// ---------------- prep kernels ----------------

__global__ void cast_f32_bf16(const float* __restrict__ in, unsigned short* __restrict__ out, int n4) {
    int i = blockIdx.x * 256 + threadIdx.x;
    if (i >= n4) return;
    float4 v = ((const float4*)in)[i];
    uint2 o;
    o.x = (unsigned)f32_to_bf16(v.x) | ((unsigned)f32_to_bf16(v.y) << 16);
    o.y = (unsigned)f32_to_bf16(v.z) | ((unsigned)f32_to_bf16(v.w) << 16);
    ((uint2*)out)[i] = o;
}

// WT[n][k] (bf16, k in [0,2K1)) from Ws[k][n], Wn[k][n] (fp32). kshift = log2(2K1).
__global__ void build_wcatT(const float* __restrict__ Ws, const float* __restrict__ Wn,
                            unsigned short* __restrict__ WT, int K1, int N, int kshift) {
    int idx = blockIdx.x * 256 + threadIdx.x;
    int Ktot = 1 << kshift;
    if (idx >= (N << kshift)) return;
    int n = idx >> kshift;
    int k = idx & (Ktot - 1);
    float v = (k < K1) ? Ws[(size_t)k * N + n] : Wn[(size_t)(k - K1) * N + n];
    WT[idx] = f32_to_bf16(v);
}

// ---------------- bf16 MFMA GEMM ----------------
// Out[M x N] = act( [Hdst | Hneigh] @ WT^T + b ), K = 2*K1, BK=32, block tile 64x64,
// 4 waves as 2x2, each wave 32x32 via 2x2 mfma_f32_16x16x32_bf16.
template <int RELU, int OUT_BF16>
__launch_bounds__(256)
__global__ void sage_gemm_mfma(const unsigned short* __restrict__ Hdst,
                               const unsigned short* __restrict__ Hneigh,
                               const unsigned short* __restrict__ WT,  // [N][2K1]
                               const float* __restrict__ bias,
                               void* __restrict__ Out,
                               int N, int K1) {
    const int Ktot = 2 * K1;
    __shared__ unsigned short As[64][56];  // [m][k], stride 112 B: 16B-aligned, <=2-way banks
    __shared__ unsigned short Bs[64][56];  // [n][k]

    const int t = threadIdx.x;
    const int lane = t & 63;
    const int w = t >> 6;
    const int wm = (w >> 1) * 32;
    const int wn = (w & 1) * 32;
    const int bm = blockIdx.y * 64;
    const int bn = blockIdx.x * 64;

    const int ldr = t >> 2;        // staging row 0..63
    const int ldk = (t & 3) * 8;   // staging k offset 0,8,16,24

    f32x4 acc[2][2] = {};

    const int ktiles = Ktot >> 5;
    for (int kt = 0; kt < ktiles; ++kt) {
        const int k0 = kt << 5;
        {   // A stage: 64 rows x 32 k
            const unsigned short* base = (k0 < K1)
                ? (Hdst + (size_t)(bm + ldr) * K1 + k0 + ldk)
                : (Hneigh + (size_t)(bm + ldr) * K1 + (k0 - K1) + ldk);
            *(uint4*)&As[ldr][ldk] = *(const uint4*)base;
        }
        {   // B stage: 64 n-rows x 32 k from WT
            int n = bn + ldr;
            uint4 v = {0, 0, 0, 0};
            if (n < N) v = *(const uint4*)(WT + (size_t)n * Ktot + k0 + ldk);
            *(uint4*)&Bs[ldr][ldk] = v;
        }
        __syncthreads();

        const int fr = lane & 15;
        const int fk = (lane >> 4) * 8;
        bf16x8 a0 = *(const bf16x8*)&As[wm + fr][fk];
        bf16x8 a1 = *(const bf16x8*)&As[wm + 16 + fr][fk];
        bf16x8 b0 = *(const bf16x8*)&Bs[wn + fr][fk];
        bf16x8 b1 = *(const bf16x8*)&Bs[wn + 16 + fr][fk];
        acc[0][0] = __builtin_amdgcn_mfma_f32_16x16x32_bf16(a0, b0, acc[0][0], 0, 0, 0);
        acc[0][1] = __builtin_amdgcn_mfma_f32_16x16x32_bf16(a0, b1, acc[0][1], 0, 0, 0);
        acc[1][0] = __builtin_amdgcn_mfma_f32_16x16x32_bf16(a1, b0, acc[1][0], 0, 0, 0);
        acc[1][1] = __builtin_amdgcn_mfma_f32_16x16x32_bf16(a1, b1, acc[1][1], 0, 0, 0);
        __syncthreads();
    }

    // epilogue: C/D layout col=lane&15, row=(lane>>4)*4+reg  [m89-verified]
    const int quad = lane >> 4;
    const int colL = lane & 15;
#pragma unroll
    for (int mt = 0; mt < 2; ++mt)
#pragma unroll
        for (int nt = 0; nt < 2; ++nt)
#pragma unroll
            for (int r = 0; r < 4; ++r) {
                int grow = bm + wm + mt * 16 + quad * 4 + r;
                int gcol = bn + wn + nt * 16 + colL;
                if (gcol < N) {
                    float v = acc[mt][nt][r] + bias[gcol];
                    if (RELU) v = fmaxf(v, 0.0f);
                    if (OUT_BF16) ((unsigned short*)Out)[(size_t)grow * N + gcol] = f32_to_bf16(v);
                    else ((float*)Out)[(size_t)grow * N + gcol] = v;
                }
            }
}

// ---------------- launch ----------------

extern "C" void kernel_launch(void* const* d_in, const int* in_sizes, int n_in,
                              void* d_out, int out_size, void* d_ws, size_t ws_size,
                              hipStream_t stream) {
    const float* x    = (const float*)d_in[0];
    const int* src0 = (const int*)d_in[1];
    const int* dst0 = (const int*)d_in[2];
    const int* src1 = (const int*)d_in[3];
    const int* dst1 = (const int*)d_in[4];
    const int* src2 = (const int*)d_in[5];
    const int* dst2 = (const int*)d_in[6];
    const float* Ws0 = (const float*)d_in[7];
    const float* Wn0 = (const float*)d_in[8];
    const float* b0  = (const float*)d_in[9];
    const float* Ws1 = (const float*)d_in[10];
    const float* Wn1 = (const float*)d_in[11];
    const float* b1  = (const float*)d_in[12];
    const float* Ws2 = (const float*)d_in[13];
    const float* Wn2 = (const float*)d_in[14];
    const float* b2  = (const float*)d_in[15];
    float* out = (float*)d_out;

    char* ws = (char*)d_ws;
    unsigned short* xcast   = (unsigned short*)(ws + 0);          // 51200*128*2 = 13,107,200
    unsigned short* h1      = (unsigned short*)(ws + 13107200);   // 51200*256*2 = 26,214,400
    unsigned short* h2      = (unsigned short*)(ws + 39321600);   // 5120*256*2  =  2,621,440
    unsigned short* hneigh0 = (unsigned short*)(ws + 41943040);   // 51200*128*2 = 13,107,200
    unsigned short* hneigh1 = (unsigned short*)(ws + 55050240);   // 5120*256*2  =  2,621,440
    unsigned short* hneigh2 = (unsigned short*)(ws + 57671680);   // 1024*256*2  =    524,288
    unsigned short* WT0     = (unsigned short*)(ws + 58195968);   // 256*256*2   =    131,072
    unsigned short* WT1     = (unsigned short*)(ws + 58327040);   // 256*512*2   =    262,144
    unsigned short* WT2     = (unsigned short*)(ws + 58589184);   // 47*512*2    =     48,128 (pad 49,168->use 49,152? keep 58,637,312 next)
    int* counts  = (int*)(ws + 58637312);                         // 51200*4
    int* offsets = (int*)(ws + 58842112);                         // 51201*4 (padded)
    int* cursor  = (int*)(ws + 59046928);                         // 51200*4
    int* csr0    = (int*)(ws + 59251728);                         // 768000*4
    int* csr1    = (int*)(ws + 62323728);                         // 51200*4
    int* csr2    = (int*)(ws + 62528528);                         // 5120*4

    // ---- one-time prep (per call) ----
    cast_f32_bf16<<<(51200 * 128 / 4 + 255) / 256, 256, 0, stream>>>(x, xcast, 51200 * 128 / 4);
    build_wcatT<<<(256 * 256 + 255) / 256, 256, 0, stream>>>(Ws0, Wn0, WT0, 128, 256, 8);
    build_wcatT<<<(256 * 512 + 255) / 256, 256, 0, stream>>>(Ws1, Wn1, WT1, 256, 256, 9);
    build_wcatT<<<(47 * 512 + 255) / 256, 256, 0, stream>>>(Ws2, Wn2, WT2, 256, 47, 9);

    // ---- Layer 0: n_src=700000(feat128 fp32), n_dst=51200, edges=768000 ----
    hipMemsetAsync(counts, 0, 51200 * 4, stream);
    hist_kernel<<<(768000 + 255) / 256, 256, 0, stream>>>(dst0, counts, 768000);
    scan_kernel<<<1, 256, 0, stream>>>(counts, offsets, cursor, 51200);
    fill_kernel<<<(768000 + 255) / 256, 256, 0, stream>>>(src0, dst0, cursor, csr0, 768000);
    gather_f32_128<<<(51200 * 64) / 256, 256, 0, stream>>>(x, csr0, offsets, hneigh0, 51200);
    {
        dim3 grid(4, 800);
        sage_gemm_mfma<1, 1><<<grid, 256, 0, stream>>>(xcast, hneigh0, WT0, b0, h1, 256, 128);
    }

    // ---- Layer 1: n_src=51200(feat256 bf16), n_dst=5120, edges=51200 ----
    hipMemsetAsync(counts, 0, 5120 * 4, stream);
    hist_kernel<<<(51200 + 255) / 256, 256, 0, stream>>>(dst1, counts, 51200);
    scan_kernel<<<1, 256, 0, stream>>>(counts, offsets, cursor, 5120);
    fill_kernel<<<(51200 + 255) / 256, 256, 0, stream>>>(src1, dst1, cursor, csr1, 51200);
    gather_bf16_256<<<(5120 * 64) / 256, 256, 0, stream>>>(h1, csr1, offsets, hneigh1, 5120);
    {
        dim3 grid(4, 80);
        sage_gemm_mfma<1, 1><<<grid, 256, 0, stream>>>(h1, hneigh1, WT1, b1, h2, 256, 256);
    }

    // ---- Layer 2: n_src=5120(feat256 bf16), n_dst=1024, edges=5120, N=47, no relu ----
    hipMemsetAsync(counts, 0, 1024 * 4, stream);
    hist_kernel<<<(5120 + 255) / 256, 256, 0, stream>>>(dst2, counts, 5120);
    scan_kernel<<<1, 256, 0, stream>>>(counts, offsets, cursor, 1024);
    fill_kernel<<<(5120 + 255) / 256, 256, 0, stream>>>(src2, dst2, cursor, csr2, 5120);
    gather_bf16_256<<<(1024 * 64) / 256, 256, 0, stream>>>(h2, csr2, offsets, hneigh2, 1024);
    {
        dim3 grid(1, 16);
        sage_gemm_mfma<0, 0><<<grid, 256, 0, stream>>>(h2, hneigh2, WT2, b2, out, 47, 256);
    }
}

// Round 3
// 744.263 us; speedup vs baseline: 1.4269x; 1.0413x over previous
//
#include <hip/hip_runtime.h>

// ---------------------------------------------------------------------------
// GraphSAGE 3-layer forward. Round 3:
//  - fused CSR build for ALL layers (1 hist, 1 scan(3 blocks,1024thr), 1 fill)
//  - fused prep (x->bf16 cast, 3 weight transposes, counts zeroing)
//  - gather: float4/uint4 per lane, 2 edges in flight per wave
//  - GEMM: 128x64 block tile, wave tile 64x32, 8 MFMA per BK=32 step
//  Harness restore/poison (~365us) is included in dur_us and is a fixed floor.
// ---------------------------------------------------------------------------

typedef __bf16 bf16x8 __attribute__((ext_vector_type(8)));
typedef float f32x4 __attribute__((ext_vector_type(4)));

static __device__ __forceinline__ unsigned short f32_to_bf16(float f) {
    unsigned u = __float_as_uint(f);
    u += 0x7fffu + ((u >> 16) & 1u);   // round-nearest-even
    return (unsigned short)(u >> 16);
}
static __device__ __forceinline__ float bf16lo(unsigned u) { return __uint_as_float(u << 16); }
static __device__ __forceinline__ float bf16hi(unsigned u) { return __uint_as_float(u & 0xffff0000u); }

// ---------------- fused prep: cast x[:51200] to bf16, build WT0/1/2, zero counts ----
__global__ void sage_prep(const float* __restrict__ x, unsigned short* __restrict__ xcast,
                          const float* __restrict__ Ws0, const float* __restrict__ Wn0,
                          const float* __restrict__ Ws1, const float* __restrict__ Wn1,
                          const float* __restrict__ Ws2, const float* __restrict__ Wn2,
                          unsigned short* __restrict__ WT0, unsigned short* __restrict__ WT1,
                          unsigned short* __restrict__ WT2, int* __restrict__ counts) {
    const int b = blockIdx.x;
    if (b < 6400) {                       // cast: 51200*128 floats, 1 float4/thread
        int i = b * 256 + threadIdx.x;
        float4 v = ((const float4*)x)[i];
        uint2 o;
        o.x = (unsigned)f32_to_bf16(v.x) | ((unsigned)f32_to_bf16(v.y) << 16);
        o.y = (unsigned)f32_to_bf16(v.z) | ((unsigned)f32_to_bf16(v.w) << 16);
        ((uint2*)xcast)[i] = o;
    } else if (b < 6656) {                // WT0: [256][256], K1=128
        int idx = (b - 6400) * 256 + threadIdx.x;
        int n = idx >> 8, k = idx & 255;
        float v = (k < 128) ? Ws0[(size_t)k * 256 + n] : Wn0[(size_t)(k - 128) * 256 + n];
        WT0[idx] = f32_to_bf16(v);
    } else if (b < 7168) {                // WT1: [256][512], K1=256
        int idx = (b - 6656) * 256 + threadIdx.x;
        int n = idx >> 9, k = idx & 511;
        float v = (k < 256) ? Ws1[(size_t)k * 256 + n] : Wn1[(size_t)(k - 256) * 256 + n];
        WT1[idx] = f32_to_bf16(v);
    } else if (b < 7262) {                // WT2: [47][512], K1=256
        int idx = (b - 7168) * 256 + threadIdx.x;
        int n = idx >> 9, k = idx & 511;
        float v = (k < 256) ? Ws2[(size_t)k * 47 + n] : Wn2[(size_t)(k - 256) * 47 + n];
        WT2[idx] = f32_to_bf16(v);
    } else {                              // zero 57344 ints (counts0|1|2 contiguous)
        int i = (b - 7262) * 256 + threadIdx.x;
        ((int4*)counts)[i] = make_int4(0, 0, 0, 0);
    }
}

// ---------------- fused hist (3 layers) ----------------
__global__ void sage_hist(const int* __restrict__ d0, int* __restrict__ c0,
                          const int* __restrict__ d1, int* __restrict__ c1,
                          const int* __restrict__ d2, int* __restrict__ c2) {
    const int b = blockIdx.x;
    if (b < 3000)       atomicAdd(&c0[d0[b * 256 + threadIdx.x]], 1);
    else if (b < 3200)  atomicAdd(&c1[d1[(b - 3000) * 256 + threadIdx.x]], 1);
    else                atomicAdd(&c2[d2[(b - 3200) * 256 + threadIdx.x]], 1);
}

// ---------------- fused scan: block b scans layer b (1024 threads) ----------------
__global__ void sage_scan(const int* __restrict__ c0, int* __restrict__ o0, int* __restrict__ u0,
                          const int* __restrict__ c1, int* __restrict__ o1, int* __restrict__ u1,
                          const int* __restrict__ c2, int* __restrict__ o2, int* __restrict__ u2) {
    const int* counts; int* offsets; int* cursor; int n;
    if (blockIdx.x == 0)      { counts = c0; offsets = o0; cursor = u0; n = 51200; }
    else if (blockIdx.x == 1) { counts = c1; offsets = o1; cursor = u1; n = 5120; }
    else                      { counts = c2; offsets = o2; cursor = u2; n = 1024; }

    __shared__ int wsum[16];
    __shared__ int wbase[16];
    __shared__ int s_carry;
    const int tid = threadIdx.x;
    const int lane = tid & 63;
    const int wid = tid >> 6;
    if (tid == 0) s_carry = 0;
    __syncthreads();

    for (int base = 0; base < n; base += 8192) {
        int idx = base + tid * 8;
        int v[8];
#pragma unroll
        for (int u = 0; u < 8; ++u) v[u] = (idx + u < n) ? counts[idx + u] : 0;
        int tsum = 0;
#pragma unroll
        for (int u = 0; u < 8; ++u) { int t = v[u]; v[u] = tsum; tsum += t; }
        int incl = tsum;
#pragma unroll
        for (int d = 1; d < 64; d <<= 1) {
            int t = __shfl_up(incl, d, 64);
            if (lane >= d) incl += t;
        }
        int wexcl = incl - tsum;
        if (lane == 63) wsum[wid] = incl;
        __syncthreads();                       // B1: wsum ready
        int carry = s_carry;
        __syncthreads();                       // B2: carry reads done
        if (tid < 64) {
            int s = (lane < 16) ? wsum[lane] : 0;
            int inc = s;
#pragma unroll
            for (int d = 1; d < 16; d <<= 1) {
                int t = __shfl_up(inc, d, 64);
                if (lane >= d) inc += t;
            }
            if (lane < 16) wbase[lane] = carry + inc - s;
            if (lane == 15) s_carry = carry + inc;
        }
        __syncthreads();                       // B3: wbase ready
        int pre = wbase[wid] + wexcl;
#pragma unroll
        for (int u = 0; u < 8; ++u)
            if (idx + u < n) { int o = pre + v[u]; offsets[idx + u] = o; cursor[idx + u] = o; }
        __syncthreads();                       // protect wsum/s_carry for next iter
    }
    if (tid == 0) offsets[n] = s_carry;
}

// ---------------- fused fill (3 layers) ----------------
__global__ void sage_fill(const int* __restrict__ s0, const int* __restrict__ d0,
                          int* __restrict__ u0, int* __restrict__ r0,
                          const int* __restrict__ s1, const int* __restrict__ d1,
                          int* __restrict__ u1, int* __restrict__ r1,
                          const int* __restrict__ s2, const int* __restrict__ d2,
                          int* __restrict__ u2, int* __restrict__ r2) {
    const int b = blockIdx.x;
    if (b < 3000) {
        int i = b * 256 + threadIdx.x;
        int pos = atomicAdd(&u0[d0[i]], 1);
        r0[pos] = s0[i];
    } else if (b < 3200) {
        int i = (b - 3000) * 256 + threadIdx.x;
        int pos = atomicAdd(&u1[d1[i]], 1);
        r1[pos] = s1[i];
    } else {
        int i = (b - 3200) * 256 + threadIdx.x;
        int pos = atomicAdd(&u2[d2[i]], 1);
        r2[pos] = s2[i];
    }
}

// ---------------- gather, feat=128 fp32 src -> bf16 out ----------------
// One wave per dst row; 32 lanes x float4 cover a row; 2 edges in flight.
__global__ void sage_gather0(const float* __restrict__ x, const int* __restrict__ csr,
                             const int* __restrict__ off, unsigned short* __restrict__ out,
                             int n_dst) {
    int row = (blockIdx.x * 256 + threadIdx.x) >> 6;
    if (row >= n_dst) return;
    const int lane = threadIdx.x & 63;
    const int half = lane >> 5;
    const int fl = lane & 31;
    const int beg = off[row], end = off[row + 1];
    const float4* hp = (const float4*)x;   // 32 float4 per row
    float4 acc = make_float4(0.f, 0.f, 0.f, 0.f);
    int i = beg;
    for (; i + 1 < end; i += 2) {
        int s = csr[i + half];
        float4 v = hp[(size_t)s * 32 + fl];
        acc.x += v.x; acc.y += v.y; acc.z += v.z; acc.w += v.w;
    }
    if (i < end && half == 0) {
        int s = csr[i];
        float4 v = hp[(size_t)s * 32 + fl];
        acc.x += v.x; acc.y += v.y; acc.z += v.z; acc.w += v.w;
    }
    acc.x += __shfl_down(acc.x, 32);
    acc.y += __shfl_down(acc.y, 32);
    acc.z += __shfl_down(acc.z, 32);
    acc.w += __shfl_down(acc.w, 32);
    if (half == 0) {
        float inv = 1.0f / fmaxf((float)(end - beg), 1.0f);
        uint2 o;
        o.x = (unsigned)f32_to_bf16(acc.x * inv) | ((unsigned)f32_to_bf16(acc.y * inv) << 16);
        o.y = (unsigned)f32_to_bf16(acc.z * inv) | ((unsigned)f32_to_bf16(acc.w * inv) << 16);
        ((uint2*)out)[(size_t)row * 32 + fl] = o;
    }
}

// ---------------- gather, feat=256 bf16 src -> bf16 out ----------------
__global__ void sage_gather256(const unsigned short* __restrict__ h, const int* __restrict__ csr,
                               const int* __restrict__ off, unsigned short* __restrict__ out,
                               int n_dst) {
    int row = (blockIdx.x * 256 + threadIdx.x) >> 6;
    if (row >= n_dst) return;
    const int lane = threadIdx.x & 63;
    const int half = lane >> 5;
    const int fl = lane & 31;
    const int beg = off[row], end = off[row + 1];
    const uint4* hp = (const uint4*)h;     // 32 uint4 (8 bf16) per row
    float a[8] = {0.f, 0.f, 0.f, 0.f, 0.f, 0.f, 0.f, 0.f};
    int i = beg;
    for (; i + 1 < end; i += 2) {
        int s = csr[i + half];
        uint4 u = hp[(size_t)s * 32 + fl];
        a[0] += bf16lo(u.x); a[1] += bf16hi(u.x);
        a[2] += bf16lo(u.y); a[3] += bf16hi(u.y);
        a[4] += bf16lo(u.z); a[5] += bf16hi(u.z);
        a[6] += bf16lo(u.w); a[7] += bf16hi(u.w);
    }
    if (i < end && half == 0) {
        int s = csr[i];
        uint4 u = hp[(size_t)s * 32 + fl];
        a[0] += bf16lo(u.x); a[1] += bf16hi(u.x);
        a[2] += bf16lo(u.y); a[3] += bf16hi(u.y);
        a[4] += bf16lo(u.z); a[5] += bf16hi(u.z);
        a[6] += bf16lo(u.w); a[7] += bf16hi(u.w);
    }
#pragma unroll
    for (int k = 0; k < 8; ++k) a[k] += __shfl_down(a[k], 32);
    if (half == 0) {
        float inv = 1.0f / fmaxf((float)(end - beg), 1.0f);
        uint4 o;
        o.x = (unsigned)f32_to_bf16(a[0] * inv) | ((unsigned)f32_to_bf16(a[1] * inv) << 16);
        o.y = (unsigned)f32_to_bf16(a[2] * inv) | ((unsigned)f32_to_bf16(a[3] * inv) << 16);
        o.z = (unsigned)f32_to_bf16(a[4] * inv) | ((unsigned)f32_to_bf16(a[5] * inv) << 16);
        o.w = (unsigned)f32_to_bf16(a[6] * inv) | ((unsigned)f32_to_bf16(a[7] * inv) << 16);
        ((uint4*)out)[(size_t)row * 32 + fl] = o;
    }
}

// ---------------- bf16 MFMA GEMM: 128x64 block tile, BK=32 ----------------
// Out[M x N] = act( [Hdst | Hneigh] @ WT^T + b ); 4 waves as 2m x 2n, wave tile 64x32.
template <int RELU, int OUT_BF16>
__launch_bounds__(256)
__global__ void sage_gemm(const unsigned short* __restrict__ Hdst,
                          const unsigned short* __restrict__ Hneigh,
                          const unsigned short* __restrict__ WT,  // [N][2K1]
                          const float* __restrict__ bias,
                          void* __restrict__ Out,
                          int N, int K1) {
    const int Ktot = 2 * K1;
    __shared__ unsigned short As[128][40];  // 80 B row stride: 16B-aligned, 2-way banks max
    __shared__ unsigned short Bs[64][40];

    const int t = threadIdx.x;
    const int lane = t & 63;
    const int w = t >> 6;
    const int wm = (w >> 1) * 64;
    const int wn = (w & 1) * 32;
    const int bm = blockIdx.y * 128;
    const int bn = blockIdx.x * 64;

    const int rowA = t >> 1;          // 0..127
    const int kA = (t & 1) * 16;      // 0 or 16
    const int rowB = t >> 2;          // 0..63
    const int kB = (t & 3) * 8;       // 0,8,16,24

    f32x4 acc[4][2] = {};

    const int ktiles = Ktot >> 5;
    for (int kt = 0; kt < ktiles; ++kt) {
        const int k0 = kt << 5;
        {   // A: 128 rows x 32 k, 2 uint4 per thread
            const unsigned short* src = (k0 < K1)
                ? (Hdst + (size_t)(bm + rowA) * K1 + k0 + kA)
                : (Hneigh + (size_t)(bm + rowA) * K1 + (k0 - K1) + kA);
            uint4 va = *(const uint4*)src;
            uint4 vb = *(const uint4*)(src + 8);
            *(uint4*)&As[rowA][kA] = va;
            *(uint4*)&As[rowA][kA + 8] = vb;
        }
        {   // B: 64 n-rows x 32 k, 1 uint4 per thread
            int n = bn + rowB;
            uint4 v = {0, 0, 0, 0};
            if (n < N) v = *(const uint4*)(WT + (size_t)n * Ktot + k0 + kB);
            *(uint4*)&Bs[rowB][kB] = v;
        }
        __syncthreads();

        const int fr = lane & 15;
        const int fk = (lane >> 4) * 8;
        bf16x8 b0 = *(const bf16x8*)&Bs[wn + fr][fk];
        bf16x8 b1 = *(const bf16x8*)&Bs[wn + 16 + fr][fk];
#pragma unroll
        for (int mt = 0; mt < 4; ++mt) {
            bf16x8 am = *(const bf16x8*)&As[wm + mt * 16 + fr][fk];
            acc[mt][0] = __builtin_amdgcn_mfma_f32_16x16x32_bf16(am, b0, acc[mt][0], 0, 0, 0);
            acc[mt][1] = __builtin_amdgcn_mfma_f32_16x16x32_bf16(am, b1, acc[mt][1], 0, 0, 0);
        }
        __syncthreads();
    }

    // epilogue: C/D layout col=lane&15, row=(lane>>4)*4+reg  [m89-verified]
    const int quad = lane >> 4;
    const int colL = lane & 15;
#pragma unroll
    for (int mt = 0; mt < 4; ++mt)
#pragma unroll
        for (int nt = 0; nt < 2; ++nt)
#pragma unroll
            for (int r = 0; r < 4; ++r) {
                int grow = bm + wm + mt * 16 + quad * 4 + r;
                int gcol = bn + wn + nt * 16 + colL;
                if (gcol < N) {
                    float v = acc[mt][nt][r] + bias[gcol];
                    if (RELU) v = fmaxf(v, 0.0f);
                    if (OUT_BF16) ((unsigned short*)Out)[(size_t)grow * N + gcol] = f32_to_bf16(v);
                    else ((float*)Out)[(size_t)grow * N + gcol] = v;
                }
            }
}

// ---------------- launch ----------------

extern "C" void kernel_launch(void* const* d_in, const int* in_sizes, int n_in,
                              void* d_out, int out_size, void* d_ws, size_t ws_size,
                              hipStream_t stream) {
    const float* x    = (const float*)d_in[0];
    const int* src0 = (const int*)d_in[1];
    const int* dst0 = (const int*)d_in[2];
    const int* src1 = (const int*)d_in[3];
    const int* dst1 = (const int*)d_in[4];
    const int* src2 = (const int*)d_in[5];
    const int* dst2 = (const int*)d_in[6];
    const float* Ws0 = (const float*)d_in[7];
    const float* Wn0 = (const float*)d_in[8];
    const float* b0  = (const float*)d_in[9];
    const float* Ws1 = (const float*)d_in[10];
    const float* Wn1 = (const float*)d_in[11];
    const float* b1  = (const float*)d_in[12];
    const float* Ws2 = (const float*)d_in[13];
    const float* Wn2 = (const float*)d_in[14];
    const float* b2  = (const float*)d_in[15];
    float* out = (float*)d_out;

    char* ws = (char*)d_ws;
    unsigned short* xcast   = (unsigned short*)(ws + 0);          // 13,107,200
    unsigned short* h1      = (unsigned short*)(ws + 13107200);   // 26,214,400
    unsigned short* h2      = (unsigned short*)(ws + 39321600);   //  2,621,440
    unsigned short* hneigh0 = (unsigned short*)(ws + 41943040);   // 13,107,200
    unsigned short* hneigh1 = (unsigned short*)(ws + 55050240);   //  2,621,440
    unsigned short* hneigh2 = (unsigned short*)(ws + 57671680);   //    524,288
    unsigned short* WT0     = (unsigned short*)(ws + 58195968);   //    131,072
    unsigned short* WT1     = (unsigned short*)(ws + 58327040);   //    262,144
    unsigned short* WT2     = (unsigned short*)(ws + 58589184);   //     48,128
    int* counts0 = (int*)(ws + 58637312);                         //    204,800
    int* counts1 = (int*)(ws + 58842112);                         //     20,480
    int* counts2 = (int*)(ws + 58862592);                         //      4,096 (counts contiguous: 229,376 B)
    int* off0    = (int*)(ws + 58866688);                         //    204,816
    int* off1    = (int*)(ws + 59071504);                         //     20,496
    int* off2    = (int*)(ws + 59092000);                         //      4,112
    int* cur0    = (int*)(ws + 59096112);                         //    204,800
    int* cur1    = (int*)(ws + 59300912);                         //     20,480
    int* cur2    = (int*)(ws + 59321392);                         //      4,096
    int* csr0    = (int*)(ws + 59325488);                         //  3,072,000
    int* csr1    = (int*)(ws + 62397488);                         //    204,800
    int* csr2    = (int*)(ws + 62602288);                         //     20,480  (end 62,622,768)

    // 1. fused prep (cast + weights + zero counts)
    sage_prep<<<7318, 256, 0, stream>>>(x, xcast, Ws0, Wn0, Ws1, Wn1, Ws2, Wn2,
                                        WT0, WT1, WT2, counts0);
    // 2-4. fused CSR build for all layers
    sage_hist<<<3220, 256, 0, stream>>>(dst0, counts0, dst1, counts1, dst2, counts2);
    sage_scan<<<3, 1024, 0, stream>>>(counts0, off0, cur0, counts1, off1, cur1, counts2, off2, cur2);
    sage_fill<<<3220, 256, 0, stream>>>(src0, dst0, cur0, csr0,
                                        src1, dst1, cur1, csr1,
                                        src2, dst2, cur2, csr2);

    // Layer 0: n_dst=51200, K1=128, N=256
    sage_gather0<<<12800, 256, 0, stream>>>(x, csr0, off0, hneigh0, 51200);
    { dim3 g(4, 400); sage_gemm<1, 1><<<g, 256, 0, stream>>>(xcast, hneigh0, WT0, b0, h1, 256, 128); }

    // Layer 1: n_dst=5120, K1=256, N=256
    sage_gather256<<<1280, 256, 0, stream>>>(h1, csr1, off1, hneigh1, 5120);
    { dim3 g(4, 40); sage_gemm<1, 1><<<g, 256, 0, stream>>>(h1, hneigh1, WT1, b1, h2, 256, 256); }

    // Layer 2: n_dst=1024, K1=256, N=47, no relu, fp32 out
    sage_gather256<<<256, 256, 0, stream>>>(h2, csr2, off2, hneigh2, 1024);
    { dim3 g(1, 8); sage_gemm<0, 0><<<g, 256, 0, stream>>>(h2, hneigh2, WT2, b2, out, 47, 256); }
}

// Round 4
// 737.821 us; speedup vs baseline: 1.4393x; 1.0087x over previous
//
#include <hip/hip_runtime.h>

// ---------------------------------------------------------------------------
// GraphSAGE 3-layer forward. Round 4:
//  - gather: 2 edges per 32-lane half (4 row-loads in flight per wave)
//  - GEMM: 128x128 block tile (BK=32), 2x2 waves of 64x64, 16 MFMA : 8 ds_read
//    per ktile; halves A-operand HBM re-reads vs round 3 (BN 64 -> 128)
// ---------------------------------------------------------------------------

typedef __bf16 bf16x8 __attribute__((ext_vector_type(8)));
typedef float f32x4 __attribute__((ext_vector_type(4)));

static __device__ __forceinline__ unsigned short f32_to_bf16(float f) {
    unsigned u = __float_as_uint(f);
    u += 0x7fffu + ((u >> 16) & 1u);   // round-nearest-even
    return (unsigned short)(u >> 16);
}
static __device__ __forceinline__ float bf16lo(unsigned u) { return __uint_as_float(u << 16); }
static __device__ __forceinline__ float bf16hi(unsigned u) { return __uint_as_float(u & 0xffff0000u); }

// ---------------- fused prep: cast x[:51200] to bf16, build WT0/1/2, zero counts ----
__global__ void sage_prep(const float* __restrict__ x, unsigned short* __restrict__ xcast,
                          const float* __restrict__ Ws0, const float* __restrict__ Wn0,
                          const float* __restrict__ Ws1, const float* __restrict__ Wn1,
                          const float* __restrict__ Ws2, const float* __restrict__ Wn2,
                          unsigned short* __restrict__ WT0, unsigned short* __restrict__ WT1,
                          unsigned short* __restrict__ WT2, int* __restrict__ counts) {
    const int b = blockIdx.x;
    if (b < 6400) {                       // cast: 51200*128 floats, 1 float4/thread
        int i = b * 256 + threadIdx.x;
        float4 v = ((const float4*)x)[i];
        uint2 o;
        o.x = (unsigned)f32_to_bf16(v.x) | ((unsigned)f32_to_bf16(v.y) << 16);
        o.y = (unsigned)f32_to_bf16(v.z) | ((unsigned)f32_to_bf16(v.w) << 16);
        ((uint2*)xcast)[i] = o;
    } else if (b < 6656) {                // WT0: [256][256], K1=128
        int idx = (b - 6400) * 256 + threadIdx.x;
        int n = idx >> 8, k = idx & 255;
        float v = (k < 128) ? Ws0[(size_t)k * 256 + n] : Wn0[(size_t)(k - 128) * 256 + n];
        WT0[idx] = f32_to_bf16(v);
    } else if (b < 7168) {                // WT1: [256][512], K1=256
        int idx = (b - 6656) * 256 + threadIdx.x;
        int n = idx >> 9, k = idx & 511;
        float v = (k < 256) ? Ws1[(size_t)k * 256 + n] : Wn1[(size_t)(k - 256) * 256 + n];
        WT1[idx] = f32_to_bf16(v);
    } else if (b < 7262) {                // WT2: [47][512], K1=256
        int idx = (b - 7168) * 256 + threadIdx.x;
        int n = idx >> 9, k = idx & 511;
        float v = (k < 256) ? Ws2[(size_t)k * 47 + n] : Wn2[(size_t)(k - 256) * 47 + n];
        WT2[idx] = f32_to_bf16(v);
    } else {                              // zero 57344 ints (counts0|1|2 contiguous)
        int i = (b - 7262) * 256 + threadIdx.x;
        ((int4*)counts)[i] = make_int4(0, 0, 0, 0);
    }
}

// ---------------- fused hist (3 layers) ----------------
__global__ void sage_hist(const int* __restrict__ d0, int* __restrict__ c0,
                          const int* __restrict__ d1, int* __restrict__ c1,
                          const int* __restrict__ d2, int* __restrict__ c2) {
    const int b = blockIdx.x;
    if (b < 3000)       atomicAdd(&c0[d0[b * 256 + threadIdx.x]], 1);
    else if (b < 3200)  atomicAdd(&c1[d1[(b - 3000) * 256 + threadIdx.x]], 1);
    else                atomicAdd(&c2[d2[(b - 3200) * 256 + threadIdx.x]], 1);
}

// ---------------- fused scan: block b scans layer b (1024 threads) ----------------
__global__ void sage_scan(const int* __restrict__ c0, int* __restrict__ o0, int* __restrict__ u0,
                          const int* __restrict__ c1, int* __restrict__ o1, int* __restrict__ u1,
                          const int* __restrict__ c2, int* __restrict__ o2, int* __restrict__ u2) {
    const int* counts; int* offsets; int* cursor; int n;
    if (blockIdx.x == 0)      { counts = c0; offsets = o0; cursor = u0; n = 51200; }
    else if (blockIdx.x == 1) { counts = c1; offsets = o1; cursor = u1; n = 5120; }
    else                      { counts = c2; offsets = o2; cursor = u2; n = 1024; }

    __shared__ int wsum[16];
    __shared__ int wbase[16];
    __shared__ int s_carry;
    const int tid = threadIdx.x;
    const int lane = tid & 63;
    const int wid = tid >> 6;
    if (tid == 0) s_carry = 0;
    __syncthreads();

    for (int base = 0; base < n; base += 8192) {
        int idx = base + tid * 8;
        int v[8];
#pragma unroll
        for (int u = 0; u < 8; ++u) v[u] = (idx + u < n) ? counts[idx + u] : 0;
        int tsum = 0;
#pragma unroll
        for (int u = 0; u < 8; ++u) { int t = v[u]; v[u] = tsum; tsum += t; }
        int incl = tsum;
#pragma unroll
        for (int d = 1; d < 64; d <<= 1) {
            int t = __shfl_up(incl, d, 64);
            if (lane >= d) incl += t;
        }
        int wexcl = incl - tsum;
        if (lane == 63) wsum[wid] = incl;
        __syncthreads();                       // B1: wsum ready
        int carry = s_carry;
        __syncthreads();                       // B2: carry reads done
        if (tid < 64) {
            int s = (lane < 16) ? wsum[lane] : 0;
            int inc = s;
#pragma unroll
            for (int d = 1; d < 16; d <<= 1) {
                int t = __shfl_up(inc, d, 64);
                if (lane >= d) inc += t;
            }
            if (lane < 16) wbase[lane] = carry + inc - s;
            if (lane == 15) s_carry = carry + inc;
        }
        __syncthreads();                       // B3: wbase ready
        int pre = wbase[wid] + wexcl;
#pragma unroll
        for (int u = 0; u < 8; ++u)
            if (idx + u < n) { int o = pre + v[u]; offsets[idx + u] = o; cursor[idx + u] = o; }
        __syncthreads();                       // protect wsum/s_carry for next iter
    }
    if (tid == 0) offsets[n] = s_carry;
}

// ---------------- fused fill (3 layers) ----------------
__global__ void sage_fill(const int* __restrict__ s0, const int* __restrict__ d0,
                          int* __restrict__ u0, int* __restrict__ r0,
                          const int* __restrict__ s1, const int* __restrict__ d1,
                          int* __restrict__ u1, int* __restrict__ r1,
                          const int* __restrict__ s2, const int* __restrict__ d2,
                          int* __restrict__ u2, int* __restrict__ r2) {
    const int b = blockIdx.x;
    if (b < 3000) {
        int i = b * 256 + threadIdx.x;
        int pos = atomicAdd(&u0[d0[i]], 1);
        r0[pos] = s0[i];
    } else if (b < 3200) {
        int i = (b - 3000) * 256 + threadIdx.x;
        int pos = atomicAdd(&u1[d1[i]], 1);
        r1[pos] = s1[i];
    } else {
        int i = (b - 3200) * 256 + threadIdx.x;
        int pos = atomicAdd(&u2[d2[i]], 1);
        r2[pos] = s2[i];
    }
}

// ---------------- gather, feat=128 fp32 src -> bf16 out ----------------
// One wave per dst row; 32 lanes x float4 cover a row; each half takes 2 edges
// per iteration (4 row-loads in flight per wave).
__global__ void sage_gather0(const float* __restrict__ x, const int* __restrict__ csr,
                             const int* __restrict__ off, unsigned short* __restrict__ out,
                             int n_dst) {
    int row = (blockIdx.x * 256 + threadIdx.x) >> 6;
    if (row >= n_dst) return;
    const int lane = threadIdx.x & 63;
    const int half = lane >> 5;
    const int fl = lane & 31;
    const int beg = off[row], end = off[row + 1];
    const float4* hp = (const float4*)x;   // 32 float4 per row
    float4 accA = make_float4(0.f, 0.f, 0.f, 0.f);
    float4 accB = make_float4(0.f, 0.f, 0.f, 0.f);
    int i = beg;
    for (; i + 3 < end; i += 4) {          // edges i..i+3: half0 {i,i+2}, half1 {i+1,i+3}
        int s0 = csr[i + half];
        int s1 = csr[i + 2 + half];
        float4 v0 = hp[(size_t)s0 * 32 + fl];
        float4 v1 = hp[(size_t)s1 * 32 + fl];
        accA.x += v0.x; accA.y += v0.y; accA.z += v0.z; accA.w += v0.w;
        accB.x += v1.x; accB.y += v1.y; accB.z += v1.z; accB.w += v1.w;
    }
    for (; i + 1 < end; i += 2) {
        int s = csr[i + half];
        float4 v = hp[(size_t)s * 32 + fl];
        accA.x += v.x; accA.y += v.y; accA.z += v.z; accA.w += v.w;
    }
    if (i < end && half == 0) {
        int s = csr[i];
        float4 v = hp[(size_t)s * 32 + fl];
        accA.x += v.x; accA.y += v.y; accA.z += v.z; accA.w += v.w;
    }
    accA.x += accB.x; accA.y += accB.y; accA.z += accB.z; accA.w += accB.w;
    accA.x += __shfl_down(accA.x, 32);
    accA.y += __shfl_down(accA.y, 32);
    accA.z += __shfl_down(accA.z, 32);
    accA.w += __shfl_down(accA.w, 32);
    if (half == 0) {
        float inv = 1.0f / fmaxf((float)(end - beg), 1.0f);
        uint2 o;
        o.x = (unsigned)f32_to_bf16(accA.x * inv) | ((unsigned)f32_to_bf16(accA.y * inv) << 16);
        o.y = (unsigned)f32_to_bf16(accA.z * inv) | ((unsigned)f32_to_bf16(accA.w * inv) << 16);
        ((uint2*)out)[(size_t)row * 32 + fl] = o;
    }
}

// ---------------- gather, feat=256 bf16 src -> bf16 out ----------------
__global__ void sage_gather256(const unsigned short* __restrict__ h, const int* __restrict__ csr,
                               const int* __restrict__ off, unsigned short* __restrict__ out,
                               int n_dst) {
    int row = (blockIdx.x * 256 + threadIdx.x) >> 6;
    if (row >= n_dst) return;
    const int lane = threadIdx.x & 63;
    const int half = lane >> 5;
    const int fl = lane & 31;
    const int beg = off[row], end = off[row + 1];
    const uint4* hp = (const uint4*)h;     // 32 uint4 (8 bf16) per row
    float a[8] = {0.f, 0.f, 0.f, 0.f, 0.f, 0.f, 0.f, 0.f};
    float b[8] = {0.f, 0.f, 0.f, 0.f, 0.f, 0.f, 0.f, 0.f};
    int i = beg;
    for (; i + 3 < end; i += 4) {
        int s0 = csr[i + half];
        int s1 = csr[i + 2 + half];
        uint4 u0 = hp[(size_t)s0 * 32 + fl];
        uint4 u1 = hp[(size_t)s1 * 32 + fl];
        a[0] += bf16lo(u0.x); a[1] += bf16hi(u0.x);
        a[2] += bf16lo(u0.y); a[3] += bf16hi(u0.y);
        a[4] += bf16lo(u0.z); a[5] += bf16hi(u0.z);
        a[6] += bf16lo(u0.w); a[7] += bf16hi(u0.w);
        b[0] += bf16lo(u1.x); b[1] += bf16hi(u1.x);
        b[2] += bf16lo(u1.y); b[3] += bf16hi(u1.y);
        b[4] += bf16lo(u1.z); b[5] += bf16hi(u1.z);
        b[6] += bf16lo(u1.w); b[7] += bf16hi(u1.w);
    }
    for (; i + 1 < end; i += 2) {
        int s = csr[i + half];
        uint4 u = hp[(size_t)s * 32 + fl];
        a[0] += bf16lo(u.x); a[1] += bf16hi(u.x);
        a[2] += bf16lo(u.y); a[3] += bf16hi(u.y);
        a[4] += bf16lo(u.z); a[5] += bf16hi(u.z);
        a[6] += bf16lo(u.w); a[7] += bf16hi(u.w);
    }
    if (i < end && half == 0) {
        int s = csr[i];
        uint4 u = hp[(size_t)s * 32 + fl];
        a[0] += bf16lo(u.x); a[1] += bf16hi(u.x);
        a[2] += bf16lo(u.y); a[3] += bf16hi(u.y);
        a[4] += bf16lo(u.z); a[5] += bf16hi(u.z);
        a[6] += bf16lo(u.w); a[7] += bf16hi(u.w);
    }
#pragma unroll
    for (int k = 0; k < 8; ++k) { a[k] += b[k]; a[k] += __shfl_down(a[k], 32); }
    if (half == 0) {
        float inv = 1.0f / fmaxf((float)(end - beg), 1.0f);
        uint4 o;
        o.x = (unsigned)f32_to_bf16(a[0] * inv) | ((unsigned)f32_to_bf16(a[1] * inv) << 16);
        o.y = (unsigned)f32_to_bf16(a[2] * inv) | ((unsigned)f32_to_bf16(a[3] * inv) << 16);
        o.z = (unsigned)f32_to_bf16(a[4] * inv) | ((unsigned)f32_to_bf16(a[5] * inv) << 16);
        o.w = (unsigned)f32_to_bf16(a[6] * inv) | ((unsigned)f32_to_bf16(a[7] * inv) << 16);
        ((uint4*)out)[(size_t)row * 32 + fl] = o;
    }
}

// ---------------- bf16 MFMA GEMM: 128x128 block tile, BK=32 ----------------
// Out[M x N] = act( [Hdst | Hneigh] @ WT^T + b ); 2x2 waves, wave tile 64x64,
// 16 MFMA + 8 ds_read_b128 per ktile. LDS stride 40 shorts (20 words): frag
// reads land 2-way bank aliased max (free, m136).
template <int RELU, int OUT_BF16>
__launch_bounds__(256)
__global__ void sage_gemm(const unsigned short* __restrict__ Hdst,
                          const unsigned short* __restrict__ Hneigh,
                          const unsigned short* __restrict__ WT,  // [N][2K1]
                          const float* __restrict__ bias,
                          void* __restrict__ Out,
                          int N, int K1) {
    const int Ktot = 2 * K1;
    __shared__ unsigned short As[128][40];
    __shared__ unsigned short Bs[128][40];

    const int t = threadIdx.x;
    const int lane = t & 63;
    const int w = t >> 6;
    const int wm = (w >> 1) * 64;
    const int wn = (w & 1) * 64;
    const int bm = blockIdx.y * 128;
    const int bn = blockIdx.x * 128;

    const int rowL = t >> 1;          // 0..127 staging row
    const int kL = (t & 1) * 16;      // 0 or 16 (two uint4 each)

    f32x4 acc[4][4] = {};

    const int ktiles = Ktot >> 5;
    for (int kt = 0; kt < ktiles; ++kt) {
        const int k0 = kt << 5;
        {   // A: 128 rows x 32 k, 2 uint4 per thread
            const unsigned short* src = (k0 < K1)
                ? (Hdst + (size_t)(bm + rowL) * K1 + k0 + kL)
                : (Hneigh + (size_t)(bm + rowL) * K1 + (k0 - K1) + kL);
            uint4 va = *(const uint4*)src;
            uint4 vb = *(const uint4*)(src + 8);
            *(uint4*)&As[rowL][kL] = va;
            *(uint4*)&As[rowL][kL + 8] = vb;
        }
        {   // B: 128 n-rows x 32 k, 2 uint4 per thread
            int n = bn + rowL;
            uint4 va = {0, 0, 0, 0}, vb = {0, 0, 0, 0};
            if (n < N) {
                const unsigned short* src = WT + (size_t)n * Ktot + k0 + kL;
                va = *(const uint4*)src;
                vb = *(const uint4*)(src + 8);
            }
            *(uint4*)&Bs[rowL][kL] = va;
            *(uint4*)&Bs[rowL][kL + 8] = vb;
        }
        __syncthreads();

        const int fr = lane & 15;
        const int fk = (lane >> 4) * 8;
        bf16x8 av[4], bv[4];
#pragma unroll
        for (int mt = 0; mt < 4; ++mt) av[mt] = *(const bf16x8*)&As[wm + mt * 16 + fr][fk];
#pragma unroll
        for (int nt = 0; nt < 4; ++nt) bv[nt] = *(const bf16x8*)&Bs[wn + nt * 16 + fr][fk];
#pragma unroll
        for (int mt = 0; mt < 4; ++mt)
#pragma unroll
            for (int nt = 0; nt < 4; ++nt)
                acc[mt][nt] = __builtin_amdgcn_mfma_f32_16x16x32_bf16(av[mt], bv[nt], acc[mt][nt], 0, 0, 0);
        __syncthreads();
    }

    // epilogue: C/D layout col=lane&15, row=(lane>>4)*4+reg  [m89-verified]
    const int quad = lane >> 4;
    const int colL = lane & 15;
#pragma unroll
    for (int mt = 0; mt < 4; ++mt)
#pragma unroll
        for (int nt = 0; nt < 4; ++nt)
#pragma unroll
            for (int r = 0; r < 4; ++r) {
                int grow = bm + wm + mt * 16 + quad * 4 + r;
                int gcol = bn + wn + nt * 16 + colL;
                if (gcol < N) {
                    float v = acc[mt][nt][r] + bias[gcol];
                    if (RELU) v = fmaxf(v, 0.0f);
                    if (OUT_BF16) ((unsigned short*)Out)[(size_t)grow * N + gcol] = f32_to_bf16(v);
                    else ((float*)Out)[(size_t)grow * N + gcol] = v;
                }
            }
}

// ---------------- launch ----------------

extern "C" void kernel_launch(void* const* d_in, const int* in_sizes, int n_in,
                              void* d_out, int out_size, void* d_ws, size_t ws_size,
                              hipStream_t stream) {
    const float* x    = (const float*)d_in[0];
    const int* src0 = (const int*)d_in[1];
    const int* dst0 = (const int*)d_in[2];
    const int* src1 = (const int*)d_in[3];
    const int* dst1 = (const int*)d_in[4];
    const int* src2 = (const int*)d_in[5];
    const int* dst2 = (const int*)d_in[6];
    const float* Ws0 = (const float*)d_in[7];
    const float* Wn0 = (const float*)d_in[8];
    const float* b0  = (const float*)d_in[9];
    const float* Ws1 = (const float*)d_in[10];
    const float* Wn1 = (const float*)d_in[11];
    const float* b1  = (const float*)d_in[12];
    const float* Ws2 = (const float*)d_in[13];
    const float* Wn2 = (const float*)d_in[14];
    const float* b2  = (const float*)d_in[15];
    float* out = (float*)d_out;

    char* ws = (char*)d_ws;
    unsigned short* xcast   = (unsigned short*)(ws + 0);          // 13,107,200
    unsigned short* h1      = (unsigned short*)(ws + 13107200);   // 26,214,400
    unsigned short* h2      = (unsigned short*)(ws + 39321600);   //  2,621,440
    unsigned short* hneigh0 = (unsigned short*)(ws + 41943040);   // 13,107,200
    unsigned short* hneigh1 = (unsigned short*)(ws + 55050240);   //  2,621,440
    unsigned short* hneigh2 = (unsigned short*)(ws + 57671680);   //    524,288
    unsigned short* WT0     = (unsigned short*)(ws + 58195968);   //    131,072
    unsigned short* WT1     = (unsigned short*)(ws + 58327040);   //    262,144
    unsigned short* WT2     = (unsigned short*)(ws + 58589184);   //     48,128
    int* counts0 = (int*)(ws + 58637312);                         //    204,800
    int* counts1 = (int*)(ws + 58842112);                         //     20,480
    int* counts2 = (int*)(ws + 58862592);                         //      4,096
    int* off0    = (int*)(ws + 58866688);                         //    204,816
    int* off1    = (int*)(ws + 59071504);                         //     20,496
    int* off2    = (int*)(ws + 59092000);                         //      4,112
    int* cur0    = (int*)(ws + 59096112);                         //    204,800
    int* cur1    = (int*)(ws + 59300912);                         //     20,480
    int* cur2    = (int*)(ws + 59321392);                         //      4,096
    int* csr0    = (int*)(ws + 59325488);                         //  3,072,000
    int* csr1    = (int*)(ws + 62397488);                         //    204,800
    int* csr2    = (int*)(ws + 62602288);                         //     20,480  (end 62,622,768)

    // 1. fused prep (cast + weights + zero counts)
    sage_prep<<<7318, 256, 0, stream>>>(x, xcast, Ws0, Wn0, Ws1, Wn1, Ws2, Wn2,
                                        WT0, WT1, WT2, counts0);
    // 2-4. fused CSR build for all layers
    sage_hist<<<3220, 256, 0, stream>>>(dst0, counts0, dst1, counts1, dst2, counts2);
    sage_scan<<<3, 1024, 0, stream>>>(counts0, off0, cur0, counts1, off1, cur1, counts2, off2, cur2);
    sage_fill<<<3220, 256, 0, stream>>>(src0, dst0, cur0, csr0,
                                        src1, dst1, cur1, csr1,
                                        src2, dst2, cur2, csr2);

    // Layer 0: n_dst=51200, K1=128, N=256
    sage_gather0<<<12800, 256, 0, stream>>>(x, csr0, off0, hneigh0, 51200);
    { dim3 g(2, 400); sage_gemm<1, 1><<<g, 256, 0, stream>>>(xcast, hneigh0, WT0, b0, h1, 256, 128); }

    // Layer 1: n_dst=5120, K1=256, N=256
    sage_gather256<<<1280, 256, 0, stream>>>(h1, csr1, off1, hneigh1, 5120);
    { dim3 g(2, 40); sage_gemm<1, 1><<<g, 256, 0, stream>>>(h1, hneigh1, WT1, b1, h2, 256, 256); }

    // Layer 2: n_dst=1024, K1=256, N=47, no relu, fp32 out
    sage_gather256<<<256, 256, 0, stream>>>(h2, csr2, off2, hneigh2, 1024);
    { dim3 g(1, 8); sage_gemm<0, 0><<<g, 256, 0, stream>>>(h2, hneigh2, WT2, b2, out, 47, 256); }
}

// Round 5
// 721.979 us; speedup vs baseline: 1.4709x; 1.0219x over previous
//
#include <hip/hip_runtime.h>

// ---------------------------------------------------------------------------
// GraphSAGE 3-layer forward. Round 5:
//  - GEMM: BK=64 (half the barriers per K), LDS 36.9 KB (still 4 blocks/CU)
//  - GEMM epilogue: LDS repack -> coalesced dwordx4 stores (N==256 bf16 path)
//  - gather0: 8-edge unroll (4 independent row loads per 32-lane half)
//  Harness floor (ws poison + input restore) ~460-490 us of dur_us is fixed.
// ---------------------------------------------------------------------------

typedef __bf16 bf16x8 __attribute__((ext_vector_type(8)));
typedef float f32x4 __attribute__((ext_vector_type(4)));

static __device__ __forceinline__ unsigned short f32_to_bf16(float f) {
    unsigned u = __float_as_uint(f);
    u += 0x7fffu + ((u >> 16) & 1u);   // round-nearest-even
    return (unsigned short)(u >> 16);
}
static __device__ __forceinline__ float bf16lo(unsigned u) { return __uint_as_float(u << 16); }
static __device__ __forceinline__ float bf16hi(unsigned u) { return __uint_as_float(u & 0xffff0000u); }

// ---------------- fused prep: cast x[:51200] to bf16, build WT0/1/2, zero counts ----
__global__ void sage_prep(const float* __restrict__ x, unsigned short* __restrict__ xcast,
                          const float* __restrict__ Ws0, const float* __restrict__ Wn0,
                          const float* __restrict__ Ws1, const float* __restrict__ Wn1,
                          const float* __restrict__ Ws2, const float* __restrict__ Wn2,
                          unsigned short* __restrict__ WT0, unsigned short* __restrict__ WT1,
                          unsigned short* __restrict__ WT2, int* __restrict__ counts) {
    const int b = blockIdx.x;
    if (b < 6400) {                       // cast: 51200*128 floats, 1 float4/thread
        int i = b * 256 + threadIdx.x;
        float4 v = ((const float4*)x)[i];
        uint2 o;
        o.x = (unsigned)f32_to_bf16(v.x) | ((unsigned)f32_to_bf16(v.y) << 16);
        o.y = (unsigned)f32_to_bf16(v.z) | ((unsigned)f32_to_bf16(v.w) << 16);
        ((uint2*)xcast)[i] = o;
    } else if (b < 6656) {                // WT0: [256][256], K1=128
        int idx = (b - 6400) * 256 + threadIdx.x;
        int n = idx >> 8, k = idx & 255;
        float v = (k < 128) ? Ws0[(size_t)k * 256 + n] : Wn0[(size_t)(k - 128) * 256 + n];
        WT0[idx] = f32_to_bf16(v);
    } else if (b < 7168) {                // WT1: [256][512], K1=256
        int idx = (b - 6656) * 256 + threadIdx.x;
        int n = idx >> 9, k = idx & 511;
        float v = (k < 256) ? Ws1[(size_t)k * 256 + n] : Wn1[(size_t)(k - 256) * 256 + n];
        WT1[idx] = f32_to_bf16(v);
    } else if (b < 7262) {                // WT2: [47][512], K1=256
        int idx = (b - 7168) * 256 + threadIdx.x;
        int n = idx >> 9, k = idx & 511;
        float v = (k < 256) ? Ws2[(size_t)k * 47 + n] : Wn2[(size_t)(k - 256) * 47 + n];
        WT2[idx] = f32_to_bf16(v);
    } else {                              // zero 57344 ints (counts0|1|2 contiguous)
        int i = (b - 7262) * 256 + threadIdx.x;
        ((int4*)counts)[i] = make_int4(0, 0, 0, 0);
    }
}

// ---------------- fused hist (3 layers) ----------------
__global__ void sage_hist(const int* __restrict__ d0, int* __restrict__ c0,
                          const int* __restrict__ d1, int* __restrict__ c1,
                          const int* __restrict__ d2, int* __restrict__ c2) {
    const int b = blockIdx.x;
    if (b < 3000)       atomicAdd(&c0[d0[b * 256 + threadIdx.x]], 1);
    else if (b < 3200)  atomicAdd(&c1[d1[(b - 3000) * 256 + threadIdx.x]], 1);
    else                atomicAdd(&c2[d2[(b - 3200) * 256 + threadIdx.x]], 1);
}

// ---------------- fused scan: block b scans layer b (1024 threads) ----------------
__global__ void sage_scan(const int* __restrict__ c0, int* __restrict__ o0, int* __restrict__ u0,
                          const int* __restrict__ c1, int* __restrict__ o1, int* __restrict__ u1,
                          const int* __restrict__ c2, int* __restrict__ o2, int* __restrict__ u2) {
    const int* counts; int* offsets; int* cursor; int n;
    if (blockIdx.x == 0)      { counts = c0; offsets = o0; cursor = u0; n = 51200; }
    else if (blockIdx.x == 1) { counts = c1; offsets = o1; cursor = u1; n = 5120; }
    else                      { counts = c2; offsets = o2; cursor = u2; n = 1024; }

    __shared__ int wsum[16];
    __shared__ int wbase[16];
    __shared__ int s_carry;
    const int tid = threadIdx.x;
    const int lane = tid & 63;
    const int wid = tid >> 6;
    if (tid == 0) s_carry = 0;
    __syncthreads();

    for (int base = 0; base < n; base += 8192) {
        int idx = base + tid * 8;
        int v[8];
#pragma unroll
        for (int u = 0; u < 8; ++u) v[u] = (idx + u < n) ? counts[idx + u] : 0;
        int tsum = 0;
#pragma unroll
        for (int u = 0; u < 8; ++u) { int t = v[u]; v[u] = tsum; tsum += t; }
        int incl = tsum;
#pragma unroll
        for (int d = 1; d < 64; d <<= 1) {
            int t = __shfl_up(incl, d, 64);
            if (lane >= d) incl += t;
        }
        int wexcl = incl - tsum;
        if (lane == 63) wsum[wid] = incl;
        __syncthreads();                       // B1: wsum ready
        int carry = s_carry;
        __syncthreads();                       // B2: carry reads done
        if (tid < 64) {
            int s = (lane < 16) ? wsum[lane] : 0;
            int inc = s;
#pragma unroll
            for (int d = 1; d < 16; d <<= 1) {
                int t = __shfl_up(inc, d, 64);
                if (lane >= d) inc += t;
            }
            if (lane < 16) wbase[lane] = carry + inc - s;
            if (lane == 15) s_carry = carry + inc;
        }
        __syncthreads();                       // B3: wbase ready
        int pre = wbase[wid] + wexcl;
#pragma unroll
        for (int u = 0; u < 8; ++u)
            if (idx + u < n) { int o = pre + v[u]; offsets[idx + u] = o; cursor[idx + u] = o; }
        __syncthreads();                       // protect wsum/s_carry for next iter
    }
    if (tid == 0) offsets[n] = s_carry;
}

// ---------------- fused fill (3 layers) ----------------
__global__ void sage_fill(const int* __restrict__ s0, const int* __restrict__ d0,
                          int* __restrict__ u0, int* __restrict__ r0,
                          const int* __restrict__ s1, const int* __restrict__ d1,
                          int* __restrict__ u1, int* __restrict__ r1,
                          const int* __restrict__ s2, const int* __restrict__ d2,
                          int* __restrict__ u2, int* __restrict__ r2) {
    const int b = blockIdx.x;
    if (b < 3000) {
        int i = b * 256 + threadIdx.x;
        int pos = atomicAdd(&u0[d0[i]], 1);
        r0[pos] = s0[i];
    } else if (b < 3200) {
        int i = (b - 3000) * 256 + threadIdx.x;
        int pos = atomicAdd(&u1[d1[i]], 1);
        r1[pos] = s1[i];
    } else {
        int i = (b - 3200) * 256 + threadIdx.x;
        int pos = atomicAdd(&u2[d2[i]], 1);
        r2[pos] = s2[i];
    }
}

// ---------------- gather, feat=128 fp32 src -> bf16 out ----------------
// One wave per dst row; 32 lanes x float4 cover a row; each half takes up to 4
// edges per iteration (8 row-loads in flight per wave).
__global__ void sage_gather0(const float* __restrict__ x, const int* __restrict__ csr,
                             const int* __restrict__ off, unsigned short* __restrict__ out,
                             int n_dst) {
    int row = (blockIdx.x * 256 + threadIdx.x) >> 6;
    if (row >= n_dst) return;
    const int lane = threadIdx.x & 63;
    const int half = lane >> 5;
    const int fl = lane & 31;
    const int beg = off[row], end = off[row + 1];
    const float4* hp = (const float4*)x + fl;   // lane-fixed column offset
    float4 accA = make_float4(0.f, 0.f, 0.f, 0.f);
    float4 accB = make_float4(0.f, 0.f, 0.f, 0.f);
    int i = beg;
    for (; i + 7 < end; i += 8) {          // half0 {i,i+2,i+4,i+6}, half1 {+1,...}
        int s0 = csr[i + half];
        int s1 = csr[i + 2 + half];
        int s2 = csr[i + 4 + half];
        int s3 = csr[i + 6 + half];
        float4 v0 = hp[(size_t)s0 * 32];
        float4 v1 = hp[(size_t)s1 * 32];
        float4 v2 = hp[(size_t)s2 * 32];
        float4 v3 = hp[(size_t)s3 * 32];
        accA.x += v0.x; accA.y += v0.y; accA.z += v0.z; accA.w += v0.w;
        accB.x += v1.x; accB.y += v1.y; accB.z += v1.z; accB.w += v1.w;
        accA.x += v2.x; accA.y += v2.y; accA.z += v2.z; accA.w += v2.w;
        accB.x += v3.x; accB.y += v3.y; accB.z += v3.z; accB.w += v3.w;
    }
    for (; i + 1 < end; i += 2) {
        int s = csr[i + half];
        float4 v = hp[(size_t)s * 32];
        accA.x += v.x; accA.y += v.y; accA.z += v.z; accA.w += v.w;
    }
    if (i < end && half == 0) {
        int s = csr[i];
        float4 v = hp[(size_t)s * 32];
        accA.x += v.x; accA.y += v.y; accA.z += v.z; accA.w += v.w;
    }
    accA.x += accB.x; accA.y += accB.y; accA.z += accB.z; accA.w += accB.w;
    accA.x += __shfl_down(accA.x, 32);
    accA.y += __shfl_down(accA.y, 32);
    accA.z += __shfl_down(accA.z, 32);
    accA.w += __shfl_down(accA.w, 32);
    if (half == 0) {
        float inv = 1.0f / fmaxf((float)(end - beg), 1.0f);
        uint2 o;
        o.x = (unsigned)f32_to_bf16(accA.x * inv) | ((unsigned)f32_to_bf16(accA.y * inv) << 16);
        o.y = (unsigned)f32_to_bf16(accA.z * inv) | ((unsigned)f32_to_bf16(accA.w * inv) << 16);
        ((uint2*)out)[(size_t)row * 32 + fl] = o;
    }
}

// ---------------- gather, feat=256 bf16 src -> bf16 out ----------------
__global__ void sage_gather256(const unsigned short* __restrict__ h, const int* __restrict__ csr,
                               const int* __restrict__ off, unsigned short* __restrict__ out,
                               int n_dst) {
    int row = (blockIdx.x * 256 + threadIdx.x) >> 6;
    if (row >= n_dst) return;
    const int lane = threadIdx.x & 63;
    const int half = lane >> 5;
    const int fl = lane & 31;
    const int beg = off[row], end = off[row + 1];
    const uint4* hp = (const uint4*)h + fl;    // 32 uint4 (8 bf16) per row
    float a[8] = {0.f, 0.f, 0.f, 0.f, 0.f, 0.f, 0.f, 0.f};
    float b[8] = {0.f, 0.f, 0.f, 0.f, 0.f, 0.f, 0.f, 0.f};
    int i = beg;
    for (; i + 3 < end; i += 4) {
        int s0 = csr[i + half];
        int s1 = csr[i + 2 + half];
        uint4 u0 = hp[(size_t)s0 * 32];
        uint4 u1 = hp[(size_t)s1 * 32];
        a[0] += bf16lo(u0.x); a[1] += bf16hi(u0.x);
        a[2] += bf16lo(u0.y); a[3] += bf16hi(u0.y);
        a[4] += bf16lo(u0.z); a[5] += bf16hi(u0.z);
        a[6] += bf16lo(u0.w); a[7] += bf16hi(u0.w);
        b[0] += bf16lo(u1.x); b[1] += bf16hi(u1.x);
        b[2] += bf16lo(u1.y); b[3] += bf16hi(u1.y);
        b[4] += bf16lo(u1.z); b[5] += bf16hi(u1.z);
        b[6] += bf16lo(u1.w); b[7] += bf16hi(u1.w);
    }
    for (; i + 1 < end; i += 2) {
        int s = csr[i + half];
        uint4 u = hp[(size_t)s * 32];
        a[0] += bf16lo(u.x); a[1] += bf16hi(u.x);
        a[2] += bf16lo(u.y); a[3] += bf16hi(u.y);
        a[4] += bf16lo(u.z); a[5] += bf16hi(u.z);
        a[6] += bf16lo(u.w); a[7] += bf16hi(u.w);
    }
    if (i < end && half == 0) {
        int s = csr[i];
        uint4 u = hp[(size_t)s * 32];
        a[0] += bf16lo(u.x); a[1] += bf16hi(u.x);
        a[2] += bf16lo(u.y); a[3] += bf16hi(u.y);
        a[4] += bf16lo(u.z); a[5] += bf16hi(u.z);
        a[6] += bf16lo(u.w); a[7] += bf16hi(u.w);
    }
#pragma unroll
    for (int k = 0; k < 8; ++k) { a[k] += b[k]; a[k] += __shfl_down(a[k], 32); }
    if (half == 0) {
        float inv = 1.0f / fmaxf((float)(end - beg), 1.0f);
        uint4 o;
        o.x = (unsigned)f32_to_bf16(a[0] * inv) | ((unsigned)f32_to_bf16(a[1] * inv) << 16);
        o.y = (unsigned)f32_to_bf16(a[2] * inv) | ((unsigned)f32_to_bf16(a[3] * inv) << 16);
        o.z = (unsigned)f32_to_bf16(a[4] * inv) | ((unsigned)f32_to_bf16(a[5] * inv) << 16);
        o.w = (unsigned)f32_to_bf16(a[6] * inv) | ((unsigned)f32_to_bf16(a[7] * inv) << 16);
        ((uint4*)out)[(size_t)row * 32 + fl] = o;
    }
}

// ---------------- bf16 MFMA GEMM: 128x128 block tile, BK=64 ----------------
// Out[M x N] = act( [Hdst | Hneigh] @ WT^T + b ); 2x2 waves, wave tile 64x64,
// 32 MFMA + 16 ds_read_b128 per ktile (2 barriers). LDS stride 72 shorts:
// fragment reads 2-way bank aliased max (free, m136). Requires K1 % 64 == 0.
// For OUT_BF16 && N==256: epilogue repacks C through LDS -> coalesced dwordx4.
template <int RELU, int OUT_BF16>
__launch_bounds__(256)
__global__ void sage_gemm(const unsigned short* __restrict__ Hdst,
                          const unsigned short* __restrict__ Hneigh,
                          const unsigned short* __restrict__ WT,  // [N][2K1]
                          const float* __restrict__ bias,
                          void* __restrict__ Out,
                          int N, int K1) {
    const int Ktot = 2 * K1;
    __shared__ unsigned short smem[2][128][72];   // 36.9 KB total
    unsigned short (*As)[72] = smem[0];
    unsigned short (*Bs)[72] = smem[1];

    const int t = threadIdx.x;
    const int lane = t & 63;
    const int w = t >> 6;
    const int wm = (w >> 1) * 64;
    const int wn = (w & 1) * 64;
    const int bm = blockIdx.y * 128;
    const int bn = blockIdx.x * 128;

    const int rowL = t >> 1;          // 0..127 staging row
    const int kL = (t & 1) * 32;      // 0 or 32 (four uint4 each)

    f32x4 acc[4][4] = {};

    const int ktiles = Ktot >> 6;     // BK=64
    for (int kt = 0; kt < ktiles; ++kt) {
        const int k0 = kt << 6;
        {   // A: 128 rows x 64 k, 4 uint4 per thread
            const unsigned short* src = (k0 < K1)
                ? (Hdst + (size_t)(bm + rowL) * K1 + k0 + kL)
                : (Hneigh + (size_t)(bm + rowL) * K1 + (k0 - K1) + kL);
            uint4 v0 = *(const uint4*)src;
            uint4 v1 = *(const uint4*)(src + 8);
            uint4 v2 = *(const uint4*)(src + 16);
            uint4 v3 = *(const uint4*)(src + 24);
            *(uint4*)&As[rowL][kL]      = v0;
            *(uint4*)&As[rowL][kL + 8]  = v1;
            *(uint4*)&As[rowL][kL + 16] = v2;
            *(uint4*)&As[rowL][kL + 24] = v3;
        }
        {   // B: 128 n-rows x 64 k, 4 uint4 per thread
            int n = bn + rowL;
            uint4 v0 = {0,0,0,0}, v1 = {0,0,0,0}, v2 = {0,0,0,0}, v3 = {0,0,0,0};
            if (n < N) {
                const unsigned short* srcB = WT + (size_t)n * Ktot + k0 + kL;
                v0 = *(const uint4*)srcB;
                v1 = *(const uint4*)(srcB + 8);
                v2 = *(const uint4*)(srcB + 16);
                v3 = *(const uint4*)(srcB + 24);
            }
            *(uint4*)&Bs[rowL][kL]      = v0;
            *(uint4*)&Bs[rowL][kL + 8]  = v1;
            *(uint4*)&Bs[rowL][kL + 16] = v2;
            *(uint4*)&Bs[rowL][kL + 24] = v3;
        }
        __syncthreads();

        const int fr = lane & 15;
        const int fk = (lane >> 4) * 8;
#pragma unroll
        for (int ks = 0; ks < 64; ks += 32) {
            bf16x8 av[4], bv[4];
#pragma unroll
            for (int mt = 0; mt < 4; ++mt) av[mt] = *(const bf16x8*)&As[wm + mt * 16 + fr][ks + fk];
#pragma unroll
            for (int nt = 0; nt < 4; ++nt) bv[nt] = *(const bf16x8*)&Bs[wn + nt * 16 + fr][ks + fk];
#pragma unroll
            for (int mt = 0; mt < 4; ++mt)
#pragma unroll
                for (int nt = 0; nt < 4; ++nt)
                    acc[mt][nt] = __builtin_amdgcn_mfma_f32_16x16x32_bf16(av[mt], bv[nt], acc[mt][nt], 0, 0, 0);
        }
        __syncthreads();
    }

    // epilogue: C/D layout col=lane&15, row=(lane>>4)*4+reg  [m89-verified]
    const int quad = lane >> 4;
    const int colL = lane & 15;
    if (OUT_BF16 && N == 256) {
        // repack via LDS (stride 136 shorts), then coalesced dwordx4 stores
        unsigned short* C = (unsigned short*)smem;   // 128 x 136 tile (34.8 KB)
#pragma unroll
        for (int mt = 0; mt < 4; ++mt)
#pragma unroll
            for (int nt = 0; nt < 4; ++nt)
#pragma unroll
                for (int r = 0; r < 4; ++r) {
                    int lrow = wm + mt * 16 + quad * 4 + r;
                    int lcol = wn + nt * 16 + colL;
                    float v = acc[mt][nt][r] + bias[bn + lcol];
                    if (RELU) v = fmaxf(v, 0.0f);
                    C[lrow * 136 + lcol] = f32_to_bf16(v);
                }
        __syncthreads();
        unsigned short* o = (unsigned short*)Out;
#pragma unroll
        for (int c = 0; c < 8; ++c) {
            int chunk = t * 8 + c;
            int row = chunk >> 4, cc = chunk & 15;     // 16 chunks of 8 shorts per row
            uint4 v = *(const uint4*)&C[row * 136 + cc * 8];
            *(uint4*)(o + (size_t)(bm + row) * N + bn + cc * 8) = v;
        }
    } else {
#pragma unroll
        for (int mt = 0; mt < 4; ++mt)
#pragma unroll
            for (int nt = 0; nt < 4; ++nt)
#pragma unroll
                for (int r = 0; r < 4; ++r) {
                    int grow = bm + wm + mt * 16 + quad * 4 + r;
                    int gcol = bn + wn + nt * 16 + colL;
                    if (gcol < N) {
                        float v = acc[mt][nt][r] + bias[gcol];
                        if (RELU) v = fmaxf(v, 0.0f);
                        if (OUT_BF16) ((unsigned short*)Out)[(size_t)grow * N + gcol] = f32_to_bf16(v);
                        else ((float*)Out)[(size_t)grow * N + gcol] = v;
                    }
                }
    }
}

// ---------------- launch ----------------

extern "C" void kernel_launch(void* const* d_in, const int* in_sizes, int n_in,
                              void* d_out, int out_size, void* d_ws, size_t ws_size,
                              hipStream_t stream) {
    const float* x    = (const float*)d_in[0];
    const int* src0 = (const int*)d_in[1];
    const int* dst0 = (const int*)d_in[2];
    const int* src1 = (const int*)d_in[3];
    const int* dst1 = (const int*)d_in[4];
    const int* src2 = (const int*)d_in[5];
    const int* dst2 = (const int*)d_in[6];
    const float* Ws0 = (const float*)d_in[7];
    const float* Wn0 = (const float*)d_in[8];
    const float* b0  = (const float*)d_in[9];
    const float* Ws1 = (const float*)d_in[10];
    const float* Wn1 = (const float*)d_in[11];
    const float* b1  = (const float*)d_in[12];
    const float* Ws2 = (const float*)d_in[13];
    const float* Wn2 = (const float*)d_in[14];
    const float* b2  = (const float*)d_in[15];
    float* out = (float*)d_out;

    char* ws = (char*)d_ws;
    unsigned short* xcast   = (unsigned short*)(ws + 0);          // 13,107,200
    unsigned short* h1      = (unsigned short*)(ws + 13107200);   // 26,214,400
    unsigned short* h2      = (unsigned short*)(ws + 39321600);   //  2,621,440
    unsigned short* hneigh0 = (unsigned short*)(ws + 41943040);   // 13,107,200
    unsigned short* hneigh1 = (unsigned short*)(ws + 55050240);   //  2,621,440
    unsigned short* hneigh2 = (unsigned short*)(ws + 57671680);   //    524,288
    unsigned short* WT0     = (unsigned short*)(ws + 58195968);   //    131,072
    unsigned short* WT1     = (unsigned short*)(ws + 58327040);   //    262,144
    unsigned short* WT2     = (unsigned short*)(ws + 58589184);   //     48,128
    int* counts0 = (int*)(ws + 58637312);                         //    204,800
    int* counts1 = (int*)(ws + 58842112);                         //     20,480
    int* counts2 = (int*)(ws + 58862592);                         //      4,096
    int* off0    = (int*)(ws + 58866688);                         //    204,816
    int* off1    = (int*)(ws + 59071504);                         //     20,496
    int* off2    = (int*)(ws + 59092000);                         //      4,112
    int* cur0    = (int*)(ws + 59096112);                         //    204,800
    int* cur1    = (int*)(ws + 59300912);                         //     20,480
    int* cur2    = (int*)(ws + 59321392);                         //      4,096
    int* csr0    = (int*)(ws + 59325488);                         //  3,072,000
    int* csr1    = (int*)(ws + 62397488);                         //    204,800
    int* csr2    = (int*)(ws + 62602288);                         //     20,480  (end 62,622,768)

    // 1. fused prep (cast + weights + zero counts)
    sage_prep<<<7318, 256, 0, stream>>>(x, xcast, Ws0, Wn0, Ws1, Wn1, Ws2, Wn2,
                                        WT0, WT1, WT2, counts0);
    // 2-4. fused CSR build for all layers
    sage_hist<<<3220, 256, 0, stream>>>(dst0, counts0, dst1, counts1, dst2, counts2);
    sage_scan<<<3, 1024, 0, stream>>>(counts0, off0, cur0, counts1, off1, cur1, counts2, off2, cur2);
    sage_fill<<<3220, 256, 0, stream>>>(src0, dst0, cur0, csr0,
                                        src1, dst1, cur1, csr1,
                                        src2, dst2, cur2, csr2);

    // Layer 0: n_dst=51200, K1=128, N=256
    sage_gather0<<<12800, 256, 0, stream>>>(x, csr0, off0, hneigh0, 51200);
    { dim3 g(2, 400); sage_gemm<1, 1><<<g, 256, 0, stream>>>(xcast, hneigh0, WT0, b0, h1, 256, 128); }

    // Layer 1: n_dst=5120, K1=256, N=256
    sage_gather256<<<1280, 256, 0, stream>>>(h1, csr1, off1, hneigh1, 5120);
    { dim3 g(2, 40); sage_gemm<1, 1><<<g, 256, 0, stream>>>(h1, hneigh1, WT1, b1, h2, 256, 256); }

    // Layer 2: n_dst=1024, K1=256, N=47, no relu, fp32 out
    sage_gather256<<<256, 256, 0, stream>>>(h2, csr2, off2, hneigh2, 1024);
    { dim3 g(1, 8); sage_gemm<0, 0><<<g, 256, 0, stream>>>(h2, hneigh2, WT2, b2, out, 47, 256); }
}